// Round 5
// baseline (1402.302 us; speedup 1.0000x reference)
//
#include <hip/hip_runtime.h>
#include <hip/hip_fp16.h>

typedef _Float16 f16;
typedef __attribute__((ext_vector_type(2))) _Float16 f16x2;
typedef __attribute__((ext_vector_type(8))) _Float16 f16x8;
typedef __attribute__((ext_vector_type(4))) float f32x4;
typedef __attribute__((ext_vector_type(8))) unsigned int u32x8;

constexpr int BATCH = 64;
constexpr int TLEN  = 2048;
constexpr int NIN   = 128;
constexpr int NHID  = 256;
constexpr int NOUT  = 128;
constexpr long MROWS = (long)BATCH * TLEN;   // 131072
constexpr float CSC = 2.8853900817779268f;   // 2*log2(e): 2^(CSC*z) = e^(2z)

__device__ __forceinline__ float exp2f_hw(float x) {
#if __has_builtin(__builtin_amdgcn_exp2f)
  return __builtin_amdgcn_exp2f(x);
#else
  return __expf(x * 0.6931471805599453f);
#endif
}
__device__ __forceinline__ float rcp_hw(float x) {
#if __has_builtin(__builtin_amdgcn_rcpf)
  return __builtin_amdgcn_rcpf(x);
#else
  return 1.0f / x;
#endif
}
__device__ __forceinline__ float fdot2f(unsigned int a, unsigned int b, float c) {
#if __has_builtin(__builtin_amdgcn_fdot2)
  return __builtin_amdgcn_fdot2(__builtin_bit_cast(f16x2, a),
                                __builtin_bit_cast(f16x2, b), c, false);
#else
  f16x2 av = __builtin_bit_cast(f16x2, a);
  f16x2 bv = __builtin_bit_cast(f16x2, b);
  return c + (float)av.x * (float)bv.x + (float)av.y * (float)bv.y;
#endif
}
// DPP: 0xB1 = quad_perm(1,0,3,2) -> lane^1 ; 0x4E = quad_perm(2,3,0,1) -> lane^2
template<int CTRL>
__device__ __forceinline__ float dpp_xor(float x) {
  int r = __builtin_amdgcn_update_dpp(0, __builtin_bit_cast(int, x),
                                      CTRL, 0xF, 0xF, true);
  return __builtin_bit_cast(float, r);
}
// partner value across lane^32 (VALU permlane on gfx950; LDS bpermute fallback)
// select convention proven correct in R15 (passed absmax 0.0039)
__device__ __forceinline__ float xor32_partner(float x, int lane) {
#if __has_builtin(__builtin_amdgcn_permlane32_swap)
  auto r = __builtin_amdgcn_permlane32_swap(
      __builtin_bit_cast(unsigned int, x), __builtin_bit_cast(unsigned int, x),
      false, false);
  unsigned int pv = (lane < 32) ? r[1] : r[0];
  return __builtin_bit_cast(float, pv);
#else
  return __builtin_bit_cast(float, __builtin_amdgcn_ds_bpermute(
      ((lane ^ 32) << 2), __builtin_bit_cast(int, x)));
#endif
}
// partner value across lane^16 — exact structural mirror of xor32_partner
__device__ __forceinline__ float xor16_partner(float x, int lane) {
#if __has_builtin(__builtin_amdgcn_permlane16_swap)
  auto r = __builtin_amdgcn_permlane16_swap(
      __builtin_bit_cast(unsigned int, x), __builtin_bit_cast(unsigned int, x),
      false, false);
  unsigned int pv = ((lane & 16) == 0) ? r[1] : r[0];
  return __builtin_bit_cast(float, pv);
#else
  return __builtin_bit_cast(float, __builtin_amdgcn_ds_bpermute(
      ((lane ^ 16) << 2), __builtin_bit_cast(int, x)));
#endif
}
// barrier that makes LDS writes visible WITHOUT draining vmcnt (global
// stores / prefetch loads keep flying across steps)
__device__ __forceinline__ void barrier_lds() {
  asm volatile("s_waitcnt lgkmcnt(0)" ::: "memory");
  __builtin_amdgcn_s_barrier();
  asm volatile("" ::: "memory");
}

// ---------------------------------------------------------------------------
// Weight convert + hi/lo split. Whh pre-scaled by CSC (tanh exp2 fold).
// f16 layout: WinH[32768] WinL[32768] WihH[65536] WihL[65536] Whh[65536] Wout[32768]
// ---------------------------------------------------------------------------
__global__ void cvt_weights(const float* __restrict__ Win, const float* __restrict__ Wih,
                            const float* __restrict__ Whh, const float* __restrict__ Wout,
                            f16* __restrict__ dst) {
  int i = blockIdx.x * blockDim.x + threadIdx.x;
  if (i < 32768) {
    float v = Win[i]; f16 h = (f16)v;
    dst[i] = h; dst[32768 + i] = (f16)(v - (float)h);
  } else if (i < 98304) {
    int j = i - 32768; float v = Wih[j]; f16 h = (f16)v;
    dst[65536 + j] = h; dst[131072 + j] = (f16)(v - (float)h);
  } else if (i < 163840) {
    int j = i - 98304; dst[196608 + j] = (f16)(CSC * Whh[j]);
  } else if (i < 196608) {
    int j = i - 163840; dst[262144 + j] = (f16)Wout[j];
  }
}

// ---------------------------------------------------------------------------
// GEMM: C[m,n] = act( sum_k A[m,k]*W[n,k] + bias[n] )   (baseline, proven)
// ---------------------------------------------------------------------------
constexpr int BM = 64, BN = 64, BK = 64;

template<int MODE>
__global__ __launch_bounds__(256)
void gemm_kernel(const void* __restrict__ Ap, const void* __restrict__ Ap2,
                 const f16* __restrict__ Bh_, const f16* __restrict__ Bl_,
                 const float* __restrict__ bias, const float* __restrict__ bias2,
                 void* __restrict__ Cp, void* __restrict__ Cp2,
                 int K, int N) {
  __shared__ __align__(16) f16 Ah[BM][BK + 8];
  __shared__ __align__(16) f16 Al[BM][BK + 8];
  __shared__ __align__(16) f16 Bh[BN][BK + 8];
  __shared__ __align__(16) f16 Bl[BN][BK + 8];

  const int tid  = threadIdx.x;
  const int lane = tid & 63;
  const int wid  = tid >> 6;
  const int wm = wid >> 1, wn = wid & 1;
  const long row0 = (long)blockIdx.x * BM;
  const int  col0 = blockIdx.y * BN;
  const int r  = tid >> 2;
  const int cc = (tid & 3) * 16;

  f32x4 acc[2][2] = {};

  for (int k0 = 0; k0 < K; k0 += BK) {
    if constexpr (MODE == 1) {
      const float* src = (const float*)Ap + (row0 + r) * (long)K + k0 + cc;
      #pragma unroll
      for (int q = 0; q < 4; ++q) {
        float4 v = ((const float4*)src)[q];
        f16 h0 = (f16)v.x, h1 = (f16)v.y, h2 = (f16)v.z, h3 = (f16)v.w;
        Ah[r][cc + 4*q + 0] = h0;  Al[r][cc + 4*q + 0] = (f16)(v.x - (float)h0);
        Ah[r][cc + 4*q + 1] = h1;  Al[r][cc + 4*q + 1] = (f16)(v.y - (float)h1);
        Ah[r][cc + 4*q + 2] = h2;  Al[r][cc + 4*q + 2] = (f16)(v.z - (float)h2);
        Ah[r][cc + 4*q + 3] = h3;  Al[r][cc + 4*q + 3] = (f16)(v.w - (float)h3);
      }
    } else if constexpr (MODE == 2) {
      const f16* sh = (const f16*)Ap  + (row0 + r) * (long)K + k0 + cc;
      const f16* sl = (const f16*)Ap2 + (row0 + r) * (long)K + k0 + cc;
      *(uint4*)&Ah[r][cc]     = *(const uint4*)sh;
      *(uint4*)&Ah[r][cc + 8] = *(const uint4*)(sh + 8);
      *(uint4*)&Al[r][cc]     = *(const uint4*)sl;
      *(uint4*)&Al[r][cc + 8] = *(const uint4*)(sl + 8);
    } else {
      const f16* sh = (const f16*)Ap + (row0 + r) * (long)K + k0 + cc;
      *(uint4*)&Ah[r][cc]     = *(const uint4*)sh;
      *(uint4*)&Ah[r][cc + 8] = *(const uint4*)(sh + 8);
    }
    {
      const f16* sh = Bh_ + (col0 + r) * (long)K + k0 + cc;
      *(uint4*)&Bh[r][cc]     = *(const uint4*)sh;
      *(uint4*)&Bh[r][cc + 8] = *(const uint4*)(sh + 8);
      if constexpr (MODE != 3) {
        const f16* sl = Bl_ + (col0 + r) * (long)K + k0 + cc;
        *(uint4*)&Bl[r][cc]     = *(const uint4*)sl;
        *(uint4*)&Bl[r][cc + 8] = *(const uint4*)(sl + 8);
      }
    }
    __syncthreads();

    #pragma unroll
    for (int ks = 0; ks < BK / 32; ++ks) {
      const int ko = ks * 32 + (lane >> 4) * 8;
      const int ra = wm * 32 + (lane & 15);
      const int rb = wn * 32 + (lane & 15);
      f16x8 a0 = *(const f16x8*)&Ah[ra][ko];
      f16x8 a1 = *(const f16x8*)&Ah[ra + 16][ko];
      f16x8 b0 = *(const f16x8*)&Bh[rb][ko];
      f16x8 b1 = *(const f16x8*)&Bh[rb + 16][ko];
      acc[0][0] = __builtin_amdgcn_mfma_f32_16x16x32_f16(a0, b0, acc[0][0], 0, 0, 0);
      acc[0][1] = __builtin_amdgcn_mfma_f32_16x16x32_f16(a0, b1, acc[0][1], 0, 0, 0);
      acc[1][0] = __builtin_amdgcn_mfma_f32_16x16x32_f16(a1, b0, acc[1][0], 0, 0, 0);
      acc[1][1] = __builtin_amdgcn_mfma_f32_16x16x32_f16(a1, b1, acc[1][1], 0, 0, 0);
      if constexpr (MODE != 3) {
        f16x8 la0 = *(const f16x8*)&Al[ra][ko];
        f16x8 la1 = *(const f16x8*)&Al[ra + 16][ko];
        f16x8 lb0 = *(const f16x8*)&Bl[rb][ko];
        f16x8 lb1 = *(const f16x8*)&Bl[rb + 16][ko];
        acc[0][0] = __builtin_amdgcn_mfma_f32_16x16x32_f16(a0, lb0, acc[0][0], 0, 0, 0);
        acc[0][0] = __builtin_amdgcn_mfma_f32_16x16x32_f16(la0, b0, acc[0][0], 0, 0, 0);
        acc[0][1] = __builtin_amdgcn_mfma_f32_16x16x32_f16(a0, lb1, acc[0][1], 0, 0, 0);
        acc[0][1] = __builtin_amdgcn_mfma_f32_16x16x32_f16(la0, b1, acc[0][1], 0, 0, 0);
        acc[1][0] = __builtin_amdgcn_mfma_f32_16x16x32_f16(a1, lb0, acc[1][0], 0, 0, 0);
        acc[1][0] = __builtin_amdgcn_mfma_f32_16x16x32_f16(la1, b0, acc[1][0], 0, 0, 0);
        acc[1][1] = __builtin_amdgcn_mfma_f32_16x16x32_f16(a1, lb1, acc[1][1], 0, 0, 0);
        acc[1][1] = __builtin_amdgcn_mfma_f32_16x16x32_f16(la1, b1, acc[1][1], 0, 0, 0);
      }
    }
    __syncthreads();
  }

  #pragma unroll
  for (int mi = 0; mi < 2; ++mi)
    #pragma unroll
    for (int ni = 0; ni < 2; ++ni)
      #pragma unroll
      for (int q = 0; q < 4; ++q) {
        long row = row0 + wm * 32 + mi * 16 + (lane >> 4) * 4 + q;
        int  col = col0 + wn * 32 + ni * 16 + (lane & 15);
        if constexpr (MODE == 1) {
          float v = fmaxf(acc[mi][ni][q] + bias[col], 0.0f);
          f16 h = (f16)v;
          ((f16*)Cp )[row * (long)N + col] = h;
          ((f16*)Cp2)[row * (long)N + col] = (f16)(v - (float)h);
        } else if constexpr (MODE == 2) {
          float v = (acc[mi][ni][q] + bias[col] + bias2[col]) * CSC;
          ((float*)Cp)[row * (long)N + col] = v;
        } else {
          ((float*)Cp)[row * (long)N + col] = acc[mi][ni][q] + bias[col];
        }
      }
}

// ---------------------------------------------------------------------------
// Recurrence R17: 1024 threads/block (16 waves), per-lane weight footprint
// halved to 32 words so register residency is cheap, plus remat made ILLEGAL.
//
// Diagnosis chain: R12/R15/R16 all ~1040-1150 cyc/step; invariant across them
// is the 128 KB/CU-step Whh flow (64 words/lane re-streamed from L2/scratch
// because the allocator refused residency at 64 words + asm pin — VGPR stuck
// at 52). Fix the PRESSURE: O=4 rows x K=16 k-slice = 32 weight words/lane
// (~75 total regs, well under the 128 cap a 16-wave block requires; R14
// proves the allocator goes to 92). Fix the LEGALITY: W2 and h16 lose
// __restrict__ -> per-step h16 stores may-alias W2 -> re-loading a weight
// after any store is unsound -> values must stay live in registers.
//
// Mapping: jj = (l&3)|(((l>>4)&1)<<2)|((l>>5)<<3) in 0..15 owns k [16jj,16jj+16)
//          G = ((l>>2)&3)|(w<<2) in 0..63 owns output rows {4G..4G+3}
//          final owned output g = 4G + 2*s1 + s0 (4x dup over lane bits 4,5)
// Reduce over 16-lane groups, xor {1,2,16,32}: stage1 xor1 keep/send (DPP),
// stage2 xor2 keep/send (DPP), stage3 xor16 all-reduce (permlane16_swap),
// stage4 xor32 all-reduce (permlane32_swap). Writers: (l&48)==0 -> LDS h,
// (l&48)==16 -> h16 global; other dups idle at write.
// LDS: 2 ds_read_b128/lane/step; chunk rotation keyed rot=(jj+(jj>>2))&1
// keeps per-instr bank aliasing at 2-way (free). 1 barrier/step (lgkmcnt
// only), 4-step unroll, rolling 4-deep pre prefetch (reads <=4KB past pre
// into the weights region of ws — allocated; values unused).
// ---------------------------------------------------------------------------
#define STEP(K, SRC, DST, P) do {                                            \
  uint4 va = *(const uint4*)((SRC) + roff0);                                 \
  uint4 vb = *(const uint4*)((SRC) + roff1);                                 \
  unsigned int hs[8] = {va.x, va.y, va.z, va.w, vb.x, vb.y, vb.z, vb.w};     \
  float sv0 = 0.f, sv1 = 0.f, sv2 = 0.f, sv3 = 0.f;                          \
  _Pragma("unroll")                                                          \
  for (int m = 0; m < 8; ++m) {                                              \
    sv0 = fdot2f(wv0[m], hs[m], sv0);                                        \
    sv1 = fdot2f(wv1[m], hs[m], sv1);                                        \
    sv2 = fdot2f(wv2[m], hs[m], sv2);                                        \
    sv3 = fdot2f(wv3[m], hs[m], sv3);                                        \
  }                                                                          \
  /* stage1 xor1: keep outputs with (i&1)==s0 (R15-proven pattern) */        \
  float k0 = s0 ? sv1 : sv0, d0 = s0 ? sv0 : sv1;                            \
  float k1 = s0 ? sv3 : sv2, d1 = s0 ? sv2 : sv3;                            \
  float t0 = k0 + dpp_xor<0xB1>(d0);                                         \
  float t1 = k1 + dpp_xor<0xB1>(d1);                                         \
  /* stage2 xor2: keep t[s1] -> output 4G+2s1+s0 */                          \
  float rk = s1 ? t1 : t0, rs = s1 ? t0 : t1;                                \
  float z2 = rk + dpp_xor<0x4E>(rs);                                         \
  /* stage3 xor16 + stage4 xor32 all-reduce */                               \
  float z3 = z2 + xor16_partner(z2, lane);                                   \
  float z  = z3 + xor32_partner(z3, lane) + (P);                             \
  float ee = exp2f_hw(z);                                                    \
  float hv = fmaxf(fmaf(-2.0f, rcp_hw(ee + 1.0f), 1.0f), 0.0f);              \
  f16 hf = (f16)hv;                                                          \
  int wsel = lane & 48;                                                      \
  if (wsel == 0)       *(f16*)((DST) + wo) = hf;   /* LDS next-h */          \
  else if (wsel == 16) hp[(K) * 256] = hf;         /* h16 global */          \
} while (0)

#define LOADW(dst, i) do {                                                   \
  _Pragma("unroll")                                                          \
  for (int c = 0; c < 2; ++c) {                                              \
    int ccw = (c + rot) & 1;                                                 \
    uint4 v = *(const uint4*)(W2 + (size_t)(4 * G + (i)) * 256               \
                              + 16 * jj + 8 * ccw);                          \
    dst[4*c+0] = v.x; dst[4*c+1] = v.y; dst[4*c+2] = v.z; dst[4*c+3] = v.w;  \
  }                                                                          \
} while (0)

__global__ __launch_bounds__(1024)
void rec_kernel(const float* __restrict__ pre, const f16* W2, f16* h16) {
  const int b    = blockIdx.x;
  const int tid  = threadIdx.x;
  const int lane = tid & 63;
  const int w    = tid >> 6;                        // wave 0..15
  const int jj   = (lane & 3) | (((lane >> 4) & 1) << 2) | ((lane >> 5) << 3);
  const int s0   = lane & 1;
  const int s1   = (lane >> 1) & 1;
  const int G    = ((lane >> 2) & 3) | (w << 2);    // 0..63
  const int g    = 4 * G + 2 * s1 + s0;             // owned output
  const int rot  = (jj + (jj >> 2)) & 1;            // bank-spread chunk pick

  __shared__ __align__(16) char hb[2][512];

  // weights: rows 4G..4G+3, k slice [16jj,16jj+16), chunk-rotated
  u32x8 wv0, wv1, wv2, wv3;
  LOADW(wv0, 0);
  LOADW(wv1, 1);
  LOADW(wv2, 2);
  LOADW(wv3, 3);
  asm volatile("" : "+v"(wv0), "+v"(wv1), "+v"(wv2), "+v"(wv3));

  if (tid < 128) ((unsigned int*)&hb[0][0])[tid] = 0u;
  __syncthreads();

  const int roff0 = 32 * jj + 16 * rot;
  const int roff1 = 32 * jj + 16 * ((1 + rot) & 1);
  const int wo    = 2 * g;

  const float* pp  = pre + (size_t)b * TLEN * 256 + g;
  f16*         hp  = h16 + (size_t)b * TLEN * 256 + g;
  const float* ppf = pp + 1024;              // t+4 prefetch pointer

  float p0 = pp[0];
  float p1 = pp[256];
  float p2 = pp[512];
  float p3 = pp[768];

  const char* hb0 = &hb[0][0];
  char*       hb1 = &hb[1][0];

  #pragma unroll 1
  for (int t = 0; t < TLEN; t += 4) {
    // issue next-quad prefetch early; lands during these 4 steps
    float n0 = ppf[0];
    float n1 = ppf[256];
    float n2 = ppf[512];
    float n3 = ppf[768];
    STEP(0, hb0, hb1, p0);
    barrier_lds();
    STEP(1, hb1, (char*)hb0, p1);
    barrier_lds();
    STEP(2, hb0, hb1, p2);
    barrier_lds();
    STEP(3, hb1, (char*)hb0, p3);
    barrier_lds();
    p0 = n0; p1 = n1; p2 = n2; p3 = n3;
    ppf += 1024;
    hp  += 1024;
  }
}

// ---------------------------------------------------------------------------
// h16 -> f32 hidden (parallel, HBM-bound). Unchanged.
// ---------------------------------------------------------------------------
__global__ __launch_bounds__(256)
void cvt_h(const f16* __restrict__ src, float* __restrict__ dst, long n) {
  long i0 = ((long)blockIdx.x * 256 + threadIdx.x) * 8;
  long stride = (long)gridDim.x * 256 * 8;
  for (long i = i0; i < n; i += stride) {
    f16x8 v = *(const f16x8*)(src + i);
    float4 a = {(float)v[0], (float)v[1], (float)v[2], (float)v[3]};
    float4 bq = {(float)v[4], (float)v[5], (float)v[6], (float)v[7]};
    *(float4*)(dst + i) = a;
    *(float4*)(dst + i + 4) = bq;
  }
}

// ---------------------------------------------------------------------------
extern "C" void kernel_launch(void* const* d_in, const int* in_sizes, int n_in,
                              void* d_out, int out_size, void* d_ws, size_t ws_size,
                              hipStream_t stream) {
  const float* input = (const float*)d_in[0];
  const float* W_in  = (const float*)d_in[1];
  const float* b_in  = (const float*)d_in[2];
  const float* W_ih  = (const float*)d_in[3];
  const float* b_ih  = (const float*)d_in[4];
  const float* W_hh  = (const float*)d_in[5];
  const float* b_hh  = (const float*)d_in[6];
  const float* W_out = (const float*)d_in[7];
  const float* b_out = (const float*)d_in[8];

  float* hidden = (float*)d_out;                   // [64,2048,256] f32
  float* outp   = (float*)d_out + MROWS * NHID;    // [64,2048,128] f32

  char* ws = (char*)d_ws;
  const size_t xh_off  = 0;
  const size_t xl_off  = (size_t)MROWS * NHID * 2;       // 64 MiB
  const size_t pre_off = xl_off * 2;                     // 128 MiB in
  const size_t w_off   = pre_off + (size_t)MROWS * NHID * 4;
  const size_t need    = w_off + 294912ull * 2;
  if (ws_size < need) return;

  f16*   x_hi  = (f16*)(ws + xh_off);
  f16*   x_lo  = (f16*)(ws + xl_off);
  float* pre   = (float*)(ws + pre_off);                 // plain [b][t][g], scaled
  f16*   wbase = (f16*)(ws + w_off);
  f16 *WinH = wbase,           *WinL = wbase + 32768;
  f16 *WihH = wbase + 65536,   *WihL = wbase + 131072;
  f16 *Whh16 = wbase + 196608, *Wout16 = wbase + 262144;
  f16* h16 = x_hi;   // alias: x consumed by G2 before rec writes h16

  cvt_weights<<<768, 256, 0, stream>>>(W_in, W_ih, W_hh, W_out, wbase);

  dim3 g12((unsigned)(MROWS / BM), NHID / BN);
  gemm_kernel<1><<<g12, 256, 0, stream>>>(input, nullptr, WinH, WinL, b_in, nullptr,
                                          x_hi, x_lo, NIN, NHID);
  gemm_kernel<2><<<g12, 256, 0, stream>>>(x_hi, x_lo, WihH, WihL, b_ih, b_hh,
                                          pre, nullptr, NHID, NHID);

  rec_kernel<<<BATCH, 1024, 0, stream>>>(pre, Whh16, h16);

  cvt_h<<<2048, 256, 0, stream>>>(h16, hidden, MROWS * NHID);

  dim3 g3((unsigned)(MROWS / BM), NOUT / BN);
  gemm_kernel<3><<<g3, 256, 0, stream>>>(h16, nullptr, Wout16, nullptr, b_out, nullptr,
                                         outp, nullptr, NHID, NOUT);
}